// Round 1
// baseline (993.284 us; speedup 1.0000x reference)
//
#include <hip/hip_runtime.h>
#include <stdint.h>

// ---------------------------------------------------------------------------
// MemoryRetrievalLayer: top-k memory retrieval.
//   Stage 1 (k_scores):  fp16 MFMA approximate scores, fused per-(q,row) top-2
//                        (packed uint: biased fp32 score, low 8 bits = slot idx)
//                        -> T[4096][512] uint2 in d_ws.
//   Stage 2 (k_select):  per query: 32nd-best threshold (binary search), collect
//                        candidates within margin, fp64-refine their best slots,
//                        exact rank (score desc, row desc on ties = reference's
//                        argsort-reversal semantics), emit all outputs.
// ---------------------------------------------------------------------------

typedef _Float16 half8 __attribute__((ext_vector_type(8)));
typedef float f32x16 __attribute__((ext_vector_type(16)));

#define NQ    512
#define NROWS 4096
#define VPR   256
#define KD    128
#define BIASF 1000.0f      // makes all packed scores positive -> uint monotone
#define MARGINF 0.5f       // >> worst-case fp16 dot error (~0.21) + pack trunc

// output layout (floats, concatenated in reference return order)
#define O_VAL 0
#define O_ENT 2097152
#define O_GID 2113536
#define O_SC  2129920
#define O_MSK 2146304
#define O_ND  2162688
#define O_AW  2162689

// ws layout
#define WS_T_BYTES (NROWS * NQ * 8)   // 16 MiB uint2 table

static __device__ __forceinline__ uint32_t umaxu(uint32_t a, uint32_t b){ return a>b?a:b; }
static __device__ __forceinline__ uint32_t uminu(uint32_t a, uint32_t b){ return a<b?a:b; }
static __device__ __forceinline__ uint32_t med3u(uint32_t a, uint32_t b, uint32_t c){
    // max(min(a,b), min(max(a,b),c)) == median -> v_med3_u32
    return umaxu(uminu(a,b), uminu(umaxu(a,b), c));
}
static __device__ __forceinline__ void t23(uint32_t a,uint32_t b,uint32_t c,uint32_t&h,uint32_t&l){
    h = umaxu(umaxu(a,b),c);   // v_max3_u32
    l = med3u(a,b,c);
}
// merge top-2 pair (H,L) with (h,l): exact top-2 of union
static __device__ __forceinline__ void mrg(uint32_t&H,uint32_t&L,uint32_t h,uint32_t l){
    uint32_t mn = uminu(H,h);
    H = umaxu(H,h);
    L = umaxu(umaxu(mn,L),l);  // max3
}

// exact top-2 of the 16 accumulator values; 'add' = slot base (half*4 + block*32)
static __device__ __forceinline__ void top2_16(const f32x16 acc, uint32_t add, uint32_t&H, uint32_t&L){
    uint32_t u[16];
    #pragma unroll
    for (int e=0;e<16;++e){
        uint32_t rm = (uint32_t)((e&3) + 8*(e>>2));   // row-map of C/D reg e (sans half)
        u[e] = (__float_as_uint(acc[e]) & 0xFFFFFF00u) | rm;
    }
    uint32_t h0,l0,h1,l1,h2,l2,h3,l3,h4,l4;
    t23(u[0],u[1],u[2],h0,l0);
    t23(u[3],u[4],u[5],h1,l1);
    t23(u[6],u[7],u[8],h2,l2);
    t23(u[9],u[10],u[11],h3,l3);
    t23(u[12],u[13],u[14],h4,l4);
    mrg(h0,l0,h1,l1);
    mrg(h2,l2,h3,l3);
    mrg(h0,l0,h2,l2);
    mrg(h0,l0,h4,l4);
    uint32_t nh = umaxu(h0,u[15]);
    uint32_t nl = med3u(h0,l0,u[15]);
    H = nh + add; L = nl + add;   // idx bits: rm(<=27/31)+add(<=228) <= 255, no carry
}

static __device__ __forceinline__ half8 to_h8(float4 a, float4 b){
    half8 h;
    h[0]=(_Float16)a.x; h[1]=(_Float16)a.y; h[2]=(_Float16)a.z; h[3]=(_Float16)a.w;
    h[4]=(_Float16)b.x; h[5]=(_Float16)b.y; h[6]=(_Float16)b.z; h[7]=(_Float16)b.w;
    return h;
}

// --------------------------- prep: q -> f16, zero n_disallowed ---------------
__global__ void k_prep(const float* __restrict__ q, _Float16* __restrict__ qf,
                       float* __restrict__ out){
    int g = blockIdx.x*256 + threadIdx.x;   // 65536 elements
    qf[g] = (_Float16)q[g];
    if (g == 0) out[O_ND] = 0.0f;
}

// --------------------------- stage 1 -----------------------------------------
#define BLKS_PER_WG 32   // 32 blocks x 32 slots = 4 rows per WG; grid = 1024
__global__ __launch_bounds__(512, 2)
void k_scores(const _Float16* __restrict__ qf, const float* __restrict__ keys,
              uint2* __restrict__ T)
{
    __shared__ _Float16 lds[2][32*KD];     // 8 KiB per buffer
    const int tid  = threadIdx.x;
    const int lane = tid & 63;
    const int wave = tid >> 6;             // 0..7 : queries [64w, 64w+64)
    const int halfid = lane >> 5;
    const int wg = blockIdx.x;
    const size_t baseSlot = (size_t)wg * (32*BLKS_PER_WG);

    // persistent B fragments (queries), f16: B[k][j], j=lane&31, k=halfid*8+e+16s
    half8 b0[8], b1[8];
    {
        const int q0 = 64*wave + (lane & 31);
        #pragma unroll
        for (int s=0;s<8;++s){
            b0[s] = *(const half8*)(qf + q0*KD + s*16 + halfid*8);
            b1[s] = *(const half8*)(qf + (q0+32)*KD + s*16 + halfid*8);
        }
    }

    // staging map: thread t -> (slot = t>>4, kgroup = t&15); global read coalesced,
    // LDS cell (kgroup*32+slot)*8 halves  ==> frag read addr = s*512 + lane*8 (conflict-free)
    const int sslot = tid >> 4;
    const int skg   = tid & 15;
    const float* gsrc = keys + (baseSlot + (size_t)sslot)*KD + skg*8;
    _Float16* ldw0 = &lds[0][(skg*32+sslot)*8];
    _Float16* ldw1 = &lds[1][(skg*32+sslot)*8];

    float4 ra = *(const float4*)(gsrc);
    float4 rb = *(const float4*)(gsrc + 4);
    *(half8*)ldw0 = to_h8(ra, rb);
    ra = *(const float4*)(gsrc + 32*KD);
    rb = *(const float4*)(gsrc + 32*KD + 4);
    __syncthreads();

    uint32_t H0=0,L0=0,H1=0,L1=0;   // running top-2 per (row, q-col), this lane-half

    #pragma unroll 2
    for (int i=0;i<BLKS_PER_WG;++i){
        const _Float16* buf = lds[i&1];
        half8 a[8];
        #pragma unroll
        for (int s=0;s<8;++s) a[s] = *(const half8*)(buf + s*512 + lane*8);

        f32x16 acc0, acc1;
        #pragma unroll
        for (int e=0;e<16;++e){ acc0[e]=BIASF; acc1[e]=BIASF; }
        #pragma unroll
        for (int s=0;s<8;++s){
            acc0 = __builtin_amdgcn_mfma_f32_32x32x16_f16(a[s], b0[s], acc0, 0,0,0);
            acc1 = __builtin_amdgcn_mfma_f32_32x32x16_f16(a[s], b1[s], acc1, 0,0,0);
        }

        // stage next block (loads for i+1 were issued last iter)
        if (i+1 < BLKS_PER_WG){
            _Float16* w = ((i+1)&1) ? ldw1 : ldw0;
            *(half8*)w = to_h8(ra, rb);
            if (i+2 < BLKS_PER_WG){
                ra = *(const float4*)(gsrc + (size_t)(i+2)*32*KD);
                rb = *(const float4*)(gsrc + (size_t)(i+2)*32*KD + 4);
            }
        }

        uint32_t add = (uint32_t)(halfid*4 + (i&7)*32);
        uint32_t h,l;
        top2_16(acc0, add, h, l); mrg(H0,L0,h,l);
        top2_16(acc1, add, h, l); mrg(H1,L1,h,l);

        if ((i&7)==7){   // row complete: cross-half merge + store
            uint32_t oh = __shfl_xor(H0, 32, 64), ol = __shfl_xor(L0, 32, 64);
            mrg(H0,L0,oh,ol);
            oh = __shfl_xor(H1, 32, 64); ol = __shfl_xor(L1, 32, 64);
            mrg(H1,L1,oh,ol);
            int row = wg*(BLKS_PER_WG/8) + (i>>3);
            uint32_t sh = (lane<32) ? H0 : H1;
            uint32_t sl = (lane<32) ? L0 : L1;
            T[(size_t)row*NQ + 64*wave + lane] = make_uint2(sh, sl);
            H0=L0=H1=L1=0;
        }
        __syncthreads();
    }
}

// --------------------------- stage 2 -----------------------------------------
static __device__ __forceinline__ double ddot128(const float* __restrict__ qv,
                                                 const float* __restrict__ k){
    double s0=0.0,s1=0.0,s2=0.0,s3=0.0;
    #pragma unroll
    for (int i=0;i<128;i+=4){
        float4 kv = *(const float4*)(k+i);
        s0 += (double)qv[i+0]*(double)kv.x;
        s1 += (double)qv[i+1]*(double)kv.y;
        s2 += (double)qv[i+2]*(double)kv.z;
        s3 += (double)qv[i+3]*(double)kv.w;
    }
    return (s0+s2)+(s1+s3);
}

__global__ __launch_bounds__(256)
void k_select(const float* __restrict__ q, const float* __restrict__ keys,
              const int* __restrict__ mident, const int* __restrict__ ment,
              const float* __restrict__ mval, const int* __restrict__ tident,
              const uint2* __restrict__ T, float* __restrict__ out)
{
    const int qi  = blockIdx.x;
    const int tid = threadIdx.x;
    __shared__ float   qv[KD];
    __shared__ uint32_t sH[128];
    __shared__ int     sRow[128];
    __shared__ double  sD[128];
    __shared__ int     sV[128];
    __shared__ int     sSel[32];
    __shared__ int     sId[32];
    __shared__ int     cnt;
    __shared__ int     redCnt[4];

    if (tid < KD) qv[tid] = q[qi*KD + tid];
    if (tid == 0) cnt = 0;

    uint32_t h[16];
    #pragma unroll
    for (int i=0;i<16;++i) h[i] = T[(size_t)(tid + 256*i)*NQ + qi].x;
    __syncthreads();

    // binary search largest t with count(H >= t) >= 32; biased values in (512,2048)
    uint32_t lo = 0x44000000u, hi = 0x45000000u;
    for (int it=0; it<24; ++it){
        uint32_t mid = (lo+hi)>>1;
        int c = 0;
        #pragma unroll
        for (int i=0;i<16;++i) c += (h[i] >= mid);
        for (int o=32;o>=1;o>>=1) c += __shfl_down(c,o,64);
        if ((tid&63)==0) redCnt[tid>>6] = c;
        __syncthreads();
        int tot = redCnt[0]+redCnt[1]+redCnt[2]+redCnt[3];
        if (tot >= 32) lo = mid; else hi = mid;
        __syncthreads();
    }

    float t32f = __uint_as_float(lo & 0xFFFFFF00u);
    uint32_t tm = __float_as_uint(t32f - MARGINF);
    #pragma unroll
    for (int i=0;i<16;++i){
        if (h[i] >= tm){
            int p = atomicAdd(&cnt, 1);
            if (p < 128){ sH[p] = h[i]; sRow[p] = tid + 256*i; }
        }
    }
    __syncthreads();
    int n = min(cnt, 128);

    // fp64 refinement of each candidate row's best slot (and runner-up if close)
    if (tid < n){
        uint32_t H = sH[tid]; int row = sRow[tid];
        uint32_t Lp = T[(size_t)row*NQ + qi].y;
        int v1 = (int)(H & 255u), v2 = (int)(Lp & 255u);
        float hf = __uint_as_float(H  & 0xFFFFFF00u);
        float lf = __uint_as_float(Lp & 0xFFFFFF00u);
        double best = ddot128(qv, keys + ((size_t)row*VPR + v1)*KD);
        int bv = v1;
        if (lf >= hf - MARGINF){
            double d2 = ddot128(qv, keys + ((size_t)row*VPR + v2)*KD);
            // reference argmax takes FIRST max (lowest slot) on exact ties
            if (d2 > best || (d2 == best && v2 < bv)){ best = d2; bv = v2; }
        }
        sD[tid] = best; sV[tid] = bv;
    }
    __syncthreads();

    // exact rank: score desc, row index DESC on ties (argsort-reversal semantics)
    if (tid < n){
        double di = sD[tid]; int ri = sRow[tid];
        int rank = 0;
        for (int j=0;j<n;++j){
            double dj = sD[j];
            rank += (dj > di) || (dj == di && sRow[j] > ri);
        }
        if (rank < 32) sSel[rank] = tid;
    }
    __syncthreads();

    if (tid < 32){
        int c   = sSel[tid];
        int row = sRow[c], v = sV[c];
        int id  = row*VPR + v;
        float sc = (float)sD[c];
        int msk = (mident[id] == tident[qi]) ? 1 : 0;
        out[O_ENT + qi*32 + tid] = (float)ment[id];
        out[O_GID + qi*32 + tid] = (float)id;
        out[O_SC  + qi*32 + tid] = sc;
        out[O_MSK + qi*32 + tid] = msk ? 1.0f : 0.0f;
        sId[tid] = id;
        float ms = sc - (msk ? 1e10f : 0.0f);
        float m = ms;
        for (int o=16;o>=1;o>>=1) m = fmaxf(m, __shfl_xor(m,o,64));
        float e = expf(ms - m);
        float ssum = e;
        for (int o=16;o>=1;o>>=1) ssum += __shfl_xor(ssum,o,64);
        out[O_AW + qi*32 + tid] = e / ssum;
        unsigned long long bal = __ballot(msk);
        if (tid == 0 && bal) atomicAdd(out + O_ND, (float)__popcll(bal));
    }
    __syncthreads();

    // top_values copy: 32 ranks x 128 floats
    {
        int r = tid >> 3, seg = tid & 7;   // 256 threads -> 32 x 8 segments of 16 floats
        const float* src = mval + (size_t)sId[r]*KD + seg*16;
        float* dst = out + O_VAL + ((size_t)qi*32 + r)*KD + seg*16;
        #pragma unroll
        for (int u=0;u<4;++u)
            *(float4*)(dst + u*4) = *(const float4*)(src + u*4);
    }
}

// --------------------------- launcher ----------------------------------------
extern "C" void kernel_launch(void* const* d_in, const int* in_sizes, int n_in,
                              void* d_out, int out_size, void* d_ws, size_t ws_size,
                              hipStream_t stream)
{
    const float* q      = (const float*)d_in[0];
    const float* keys   = (const float*)d_in[1];
    const int*   mident = (const int*)d_in[2];
    const int*   ment   = (const int*)d_in[3];
    const float* mval   = (const float*)d_in[4];
    const int*   tident = (const int*)d_in[5];
    float* out = (float*)d_out;

    uint2*     T  = (uint2*)d_ws;
    _Float16*  qf = (_Float16*)((char*)d_ws + WS_T_BYTES);

    k_prep  <<<NQ*KD/256, 256, 0, stream>>>(q, qf, out);
    k_scores<<<1024, 512, 0, stream>>>(qf, keys, T);
    k_select<<<NQ, 256, 0, stream>>>(q, keys, mident, ment, mval, tident, T, out);
}